// Round 1
// baseline (523.237 us; speedup 1.0000x reference)
//
#include <hip/hip_runtime.h>

#define OBS_T 20
#define HID 128
#define NGATE 512
#define MB 16          // batch rows per block
#define HSTR 136       // LDS h row stride in bf16 elems (272B = 17*16B aligned, 4-bank skew)

typedef __bf16 bf16x8 __attribute__((ext_vector_type(8)));
typedef __bf16 bf16x4 __attribute__((ext_vector_type(4)));
typedef float f32x4 __attribute__((ext_vector_type(4)));

__device__ __forceinline__ float fast_rcp(float x) { return __builtin_amdgcn_rcpf(x); }
__device__ __forceinline__ float sigm(float x) { return fast_rcp(1.0f + __expf(-x)); }
__device__ __forceinline__ float tanh_f(float x) {
  return 1.0f - 2.0f * fast_rcp(1.0f + __expf(2.0f * x));
}

// ---- prep 1: fold embedding into rank-2 + bias, permuted to MFMA column order ----
// permutation: gate row r (torch order i,f,g,o; r = q*128 + j_global) maps to
// n_perm = ng*128 + tn*16 + cn  with ng=j>>5, tn=q*2+((j&31)>>4), cn=j&15
__global__ void prep_vec(const float* __restrict__ W_emb, const float* __restrict__ b_emb,
                         const float* __restrict__ W_ih, const float* __restrict__ b_ih,
                         const float* __restrict__ b_hh,
                         float* __restrict__ biasp, float* __restrict__ wx0p,
                         float* __restrict__ wx1p) {
  int r = blockIdx.x * blockDim.x + threadIdx.x;
  if (r >= NGATE) return;
  float s0 = 0.f, s1 = 0.f, sb = 0.f;
  for (int d = 0; d < 64; ++d) {
    float w = W_ih[r * 64 + d];
    s0 += w * W_emb[d * 2 + 0];
    s1 += w * W_emb[d * 2 + 1];
    sb += w * b_emb[d];
  }
  int q = r >> 7, j = r & 127;
  int ng = j >> 5, jl = j & 31;
  int tn = q * 2 + (jl >> 4), cn = jl & 15;
  int np = ng * 128 + tn * 16 + cn;
  biasp[np] = b_ih[r] + b_hh[r] + sb;
  wx0p[np] = s0;
  wx1p[np] = s1;
}

// ---- prep 2: W_hh -> bf16 B-fragments, laid out exactly as the main kernel loads them ----
// flat elem = (((ng*4+kstep)*8+tn)*64 + lane)*8 + jj
// B[k][n]: n -> (ng,tn,cn=lane&15), k = kstep*32 + (lane>>4)*8 + jj ; B[k][n] = W_hh[r(n)][k]
__global__ void prep_wp(const float* __restrict__ W_hh, __bf16* __restrict__ Wp) {
  int tid = blockIdx.x * blockDim.x + threadIdx.x;  // 0..65535
  int jj = tid & 7;
  int lane = (tid >> 3) & 63;
  int tn = (tid >> 9) & 7;
  int kstep = (tid >> 12) & 3;
  int ng = (tid >> 14) & 3;
  int cn = lane & 15, quad = lane >> 4;
  int q = tn >> 1;
  int jg = ng * 32 + (tn & 1) * 16 + cn;
  int r = q * 128 + jg;
  int k = kstep * 32 + quad * 8 + jj;
  Wp[tid] = (__bf16)W_hh[r * 128 + k];
}

// ---- main fused LSTM kernel ----
__global__ __launch_bounds__(256, 2) void lstm_fused(
    const float* __restrict__ obs, const float* __restrict__ h0,
    const float* __restrict__ c0, const __bf16* __restrict__ Wp,
    const float* __restrict__ biasp, const float* __restrict__ wx0p,
    const float* __restrict__ wx1p, float* __restrict__ out, int batch) {
  __shared__ __align__(16) __bf16 hbuf[2][MB][HSTR];
  __shared__ __align__(16) float obs_s[OBS_T][MB][2];

  const int tid = threadIdx.x;
  const int lane = tid & 63;
  const int wv = tid >> 6;  // wave id = gate-column group (0..3)
  const int cn = lane & 15;
  const int quad = lane >> 4;
  const int bbase = blockIdx.x * MB;

  // stage obs tile: [20][16][2] fp32 = 160 float4
  if (tid < OBS_T * MB * 2 / 4) {
    const int t = tid >> 3, f4 = tid & 7;
    ((float4*)obs_s)[tid] = ((const float4*)obs)[(t * batch + bbase) / 2 + f4];
  }
  // stage h0 tile fp32 -> bf16 LDS
#pragma unroll
  for (int it = 0; it < 2; ++it) {
    int idx = tid + it * 256;  // 0..511, 16 rows x 32 float4
    int row = idx >> 5, c4 = idx & 31;
    float4 v = ((const float4*)h0)[(bbase + row) * 32 + c4];
    bf16x4 b;
    b.x = (__bf16)v.x; b.y = (__bf16)v.y; b.z = (__bf16)v.z; b.w = (__bf16)v.w;
    *(bf16x4*)&hbuf[0][row][c4 * 4] = b;
  }

  // persistent B fragments: 4 ksteps x 8 ntiles x 16B/lane = 128 VGPRs
  bf16x8 Bf[4][8];
  {
    const bf16x8* wp8 = (const bf16x8*)Wp;
#pragma unroll
    for (int ks = 0; ks < 4; ++ks)
#pragma unroll
      for (int tn = 0; tn < 8; ++tn)
        Bf[ks][tn] = wp8[((wv * 4 + ks) * 8 + tn) * 64 + lane];
  }

  float bias_v[8], wx0_v[8], wx1_v[8];
#pragma unroll
  for (int tn = 0; tn < 8; ++tn) {
    int n = wv * 128 + tn * 16 + cn;
    bias_v[tn] = biasp[n];
    wx0_v[tn] = wx0p[n];
    wx1_v[tn] = wx1p[n];
  }

  // c state: lane owns (m = quad*4+r) x (j = wv*32 + jhi*16 + cn), fp32 all the way
  float cc[2][4];
#pragma unroll
  for (int jhi = 0; jhi < 2; ++jhi)
#pragma unroll
    for (int r = 0; r < 4; ++r)
      cc[jhi][r] = c0[(bbase + quad * 4 + r) * HID + wv * 32 + jhi * 16 + cn];

  __syncthreads();

  int cur = 0;
  for (int t = 0; t < OBS_T; ++t) {
    // A fragments: A[m=cn][k = ks*32 + quad*8 + j]
    bf16x8 A[4];
#pragma unroll
    for (int ks = 0; ks < 4; ++ks)
      A[ks] = *(const bf16x8*)&hbuf[cur][cn][ks * 32 + quad * 8];

    // obs for this lane's 4 batch rows
    float4 ob0 = *(const float4*)&obs_s[t][quad * 4][0];
    float4 ob1 = *(const float4*)&obs_s[t][quad * 4 + 2][0];
    float o0r[4] = {ob0.x, ob0.z, ob1.x, ob1.z};
    float o1r[4] = {ob0.y, ob0.w, ob1.y, ob1.w};

    // acc init = bias + rank-2 folded embedding (fp32, exact)
    f32x4 acc[8];
#pragma unroll
    for (int tn = 0; tn < 8; ++tn)
#pragma unroll
      for (int r = 0; r < 4; ++r)
        acc[tn][r] = fmaf(o1r[r], wx1_v[tn], fmaf(o0r[r], wx0_v[tn], bias_v[tn]));

    // gates += h @ W_hh^T  (32 MFMAs)
#pragma unroll
    for (int ks = 0; ks < 4; ++ks)
#pragma unroll
      for (int tn = 0; tn < 8; ++tn)
        acc[tn] = __builtin_amdgcn_mfma_f32_16x16x32_bf16(A[ks], Bf[ks][tn], acc[tn], 0, 0, 0);

    const int last = (t == OBS_T - 1);
    // update: tn = 2*q + jhi holds gate q for unit j = wv*32 + jhi*16 + cn
#pragma unroll
    for (int jhi = 0; jhi < 2; ++jhi) {
#pragma unroll
      for (int r = 0; r < 4; ++r) {
        float gi = acc[0 + jhi][r];
        float gf = acc[2 + jhi][r];
        float gg = acc[4 + jhi][r];
        float go = acc[6 + jhi][r];
        float iv = sigm(gi);
        float fv = sigm(gf);
        float gv = tanh_f(gg);
        float ov = sigm(go);
        float c = fmaf(fv, cc[jhi][r], iv * gv);
        cc[jhi][r] = c;
        float h = ov * tanh_f(c);
        int m = quad * 4 + r;
        int j = wv * 32 + jhi * 16 + cn;
        if (last) {
          out[(bbase + m) * HID + j] = h;
        } else {
          hbuf[cur ^ 1][m][j] = (__bf16)h;
        }
      }
    }
    __syncthreads();
    cur ^= 1;
  }
}

extern "C" void kernel_launch(void* const* d_in, const int* in_sizes, int n_in,
                              void* d_out, int out_size, void* d_ws, size_t ws_size,
                              hipStream_t stream) {
  const float* obs = (const float*)d_in[0];
  const float* h0 = (const float*)d_in[1];
  const float* c0 = (const float*)d_in[2];
  const float* W_emb = (const float*)d_in[3];
  const float* b_emb = (const float*)d_in[4];
  const float* W_ih = (const float*)d_in[5];
  const float* W_hh = (const float*)d_in[6];
  const float* b_ih = (const float*)d_in[7];
  const float* b_hh = (const float*)d_in[8];
  float* out = (float*)d_out;
  const int batch = in_sizes[1] / HID;

  __bf16* Wp = (__bf16*)d_ws;                       // 65536 bf16 = 128 KB
  float* biasp = (float*)((char*)d_ws + 131072);    // 512 f32
  float* wx0p = biasp + NGATE;
  float* wx1p = wx0p + NGATE;

  prep_vec<<<2, 256, 0, stream>>>(W_emb, b_emb, W_ih, b_ih, b_hh, biasp, wx0p, wx1p);
  prep_wp<<<256, 256, 0, stream>>>(W_hh, Wp);
  lstm_fused<<<batch / MB, 256, 0, stream>>>(obs, h0, c0, Wp, biasp, wx0p, wx1p, out, batch);
}